// Round 1
// baseline (636.513 us; speedup 1.0000x reference)
//
#include <hip/hip_runtime.h>

#define NCH 256   // channels (c_in == c_hid == 256)

// ---------------- CSR build ----------------
__global__ __launch_bounds__(256) void k_init_deg(int* __restrict__ deg, int n) {
    int i = blockIdx.x * 256 + threadIdx.x;
    if (i < n) deg[i] = 1;  // self-loop
}

__global__ __launch_bounds__(256) void k_hist(const int* __restrict__ dst, int E,
                                              int* __restrict__ deg) {
    int e = blockIdx.x * 256 + threadIdx.x;
    if (e < E) atomicAdd(&deg[dst[e]], 1);
}

// per-block exclusive scan of (deg-1) over chunks of 1024 (256 thr x 4)
__global__ __launch_bounds__(256) void k_scan_blk(const int* __restrict__ deg,
                                                  int* __restrict__ part,
                                                  int* __restrict__ bsum, int N) {
    __shared__ int sm[256];
    int t = threadIdx.x;
    int base = blockIdx.x * 1024 + t * 4;
    int v[4]; int s = 0;
#pragma unroll
    for (int j = 0; j < 4; ++j) {
        int i = base + j;
        int d = (i < N) ? (deg[i] - 1) : 0;
        v[j] = d; s += d;
    }
    sm[t] = s; __syncthreads();
#pragma unroll
    for (int off = 1; off < 256; off <<= 1) {
        int u = (t >= off) ? sm[t - off] : 0;
        __syncthreads();
        sm[t] += u;
        __syncthreads();
    }
    int excl = sm[t] - s;
#pragma unroll
    for (int j = 0; j < 4; ++j) {
        int i = base + j;
        if (i < N) part[i] = excl;
        excl += v[j];
    }
    if (t == 255) bsum[blockIdx.x] = sm[255];
}

// single-wave scan of block sums (nb <= 64)
__global__ void k_scan_top(int* __restrict__ bsum, int nb, int* __restrict__ rowptr_end) {
    int t = threadIdx.x;  // 64 threads
    int orig = (t < nb) ? bsum[t] : 0;
    int v = orig;
#pragma unroll
    for (int off = 1; off < 64; off <<= 1) {
        int u = __shfl_up(v, off, 64);
        if (t >= off) v += u;
    }
    if (t < nb) bsum[t] = v - orig;   // exclusive block offset
    if (t == 63) *rowptr_end = v;     // total edge count
}

__global__ __launch_bounds__(256) void k_finalize(const int* __restrict__ deg,
                                                  int* __restrict__ row_ptr,
                                                  const int* __restrict__ boff,
                                                  int* __restrict__ cursor,
                                                  float* __restrict__ dinv, int N) {
    int i = blockIdx.x * 256 + threadIdx.x;
    if (i < N) {
        int rp = row_ptr[i] + boff[i >> 10];
        row_ptr[i] = rp;
        cursor[i]  = rp;
        dinv[i] = rsqrtf((float)deg[i]);  // deg >= 1 always (self-loop)
    }
}

__global__ __launch_bounds__(256) void k_scatter(const int* __restrict__ src,
                                                 const int* __restrict__ dst, int E,
                                                 int* __restrict__ cursor,
                                                 int* __restrict__ col) {
    int e = blockIdx.x * 256 + threadIdx.x;
    if (e < E) {
        int d = dst[e];
        int pos = atomicAdd(&cursor[d], 1);
        col[pos] = src[e];
    }
}

// ---------------- f32 GEMM: C[M,256] = A[M,256] @ W[256,256] ----------------
// 64x64 tile, 256 threads, 4x4 microtile, K-step 16.
__global__ __launch_bounds__(256) void k_gemm_f32(const float* __restrict__ A,
                                                  const float* __restrict__ W,
                                                  float* __restrict__ Cout, int M) {
    __shared__ float As[16][68];  // [k][row], pad 4 keeps 16B align + banks spread
    __shared__ float Bs[16][68];  // [k][col]

    const int tid = threadIdx.x;
    const int tx = tid & 15;       // col group
    const int ty = tid >> 4;       // row group
    const int m0 = blockIdx.x * 64;
    const int n0 = blockIdx.y * 64;

    const int ar = tid >> 2;            // 0..63 row in tile
    const int ak = (tid & 3) << 2;      // 0,4,8,12
    const int bk = tid >> 4;            // 0..15
    const int bn = (tid & 15) << 2;     // 0..60

    int arow = m0 + ar; if (arow >= M) arow = M - 1;

    float acc[4][4] = {};

    for (int k0 = 0; k0 < 256; k0 += 16) {
        float4 av = *(const float4*)&A[(size_t)arow * NCH + k0 + ak];
        float4 bv = *(const float4*)&W[(size_t)(k0 + bk) * NCH + n0 + bn];
        __syncthreads();
        As[ak + 0][ar] = av.x;
        As[ak + 1][ar] = av.y;
        As[ak + 2][ar] = av.z;
        As[ak + 3][ar] = av.w;
        *(float4*)&Bs[bk][bn] = bv;
        __syncthreads();
#pragma unroll
        for (int kk = 0; kk < 16; ++kk) {
            float4 a4 = *(const float4*)&As[kk][ty * 4];
            float4 b4 = *(const float4*)&Bs[kk][tx * 4];
            acc[0][0] += a4.x * b4.x; acc[0][1] += a4.x * b4.y;
            acc[0][2] += a4.x * b4.z; acc[0][3] += a4.x * b4.w;
            acc[1][0] += a4.y * b4.x; acc[1][1] += a4.y * b4.y;
            acc[1][2] += a4.y * b4.z; acc[1][3] += a4.y * b4.w;
            acc[2][0] += a4.z * b4.x; acc[2][1] += a4.z * b4.y;
            acc[2][2] += a4.z * b4.z; acc[2][3] += a4.z * b4.w;
            acc[3][0] += a4.w * b4.x; acc[3][1] += a4.w * b4.y;
            acc[3][2] += a4.w * b4.z; acc[3][3] += a4.w * b4.w;
        }
    }

#pragma unroll
    for (int i = 0; i < 4; ++i) {
        int row = m0 + ty * 4 + i;
        if (row < M) {
            float4 o = make_float4(acc[i][0], acc[i][1], acc[i][2], acc[i][3]);
            *(float4*)&Cout[(size_t)row * NCH + n0 + tx * 4] = o;
        }
    }
}

// ---------------- aggregation: out[v] = relu(dv*(sum dinv[s]*h[s] + dv*h[v]) + b) ----
__global__ __launch_bounds__(256) void k_agg(const float* __restrict__ h,
                                             const float* __restrict__ dinv,
                                             const int* __restrict__ row_ptr,
                                             const int* __restrict__ col,
                                             const float* __restrict__ bias,
                                             float* __restrict__ out) {
    __shared__ int   scol[256];
    __shared__ float sdw[256];
    int v = blockIdx.x;
    int ch = threadIdx.x;
    float dv = dinv[v];
    float acc = dv * h[(size_t)v * NCH + ch];   // self-loop (x dv again at end)
    int beg = row_ptr[v], end = row_ptr[v + 1];
    for (int cb = beg; cb < end; cb += 256) {
        int n = min(256, end - cb);
        __syncthreads();
        if (ch < n) {
            int s = col[cb + ch];
            scol[ch] = s;
            sdw[ch] = dinv[s];
        }
        __syncthreads();
        for (int j = 0; j < n; ++j) {
            acc += sdw[j] * h[(size_t)scol[j] * NCH + ch];
        }
    }
    float r = dv * acc + bias[ch];
    out[(size_t)v * NCH + ch] = fmaxf(r, 0.0f);
}

// ---------------- mean pool over sorted batch ids ----------------
__device__ __forceinline__ int lower_bound_i(const int* a, int n, int key) {
    int lo = 0, hi = n;
    while (lo < hi) {
        int mid = (lo + hi) >> 1;
        if (a[mid] < key) lo = mid + 1; else hi = mid;
    }
    return lo;
}

__global__ __launch_bounds__(256) void k_pool(const float* __restrict__ a,
                                              const int* __restrict__ batch,
                                              float* __restrict__ out, int N) {
    int g = blockIdx.x;     // 0..127
    int ch = threadIdx.x;
    int lo = lower_bound_i(batch, N, g);
    int hi = lower_bound_i(batch, N, g + 1);
    float s = 0.0f;
    for (int i = lo; i < hi; ++i) s += a[(size_t)i * NCH + ch];
    int cnt = hi - lo;
    out[(size_t)g * NCH + ch] = s / (float)max(cnt, 1);
}

// ---------------- host ----------------
extern "C" void kernel_launch(void* const* d_in, const int* in_sizes, int n_in,
                              void* d_out, int out_size, void* d_ws, size_t ws_size,
                              hipStream_t stream) {
    const float* x     = (const float*)d_in[0];
    const int*   ei    = (const int*)d_in[1];
    const int*   batch = (const int*)d_in[2];
    const float* W1    = (const float*)d_in[3];
    const float* b1    = (const float*)d_in[4];
    const float* W2    = (const float*)d_in[5];
    const float* b2    = (const float*)d_in[6];
    float* out = (float*)d_out;

    const int M = in_sizes[0] / NCH;   // 50000 nodes
    const int E = in_sizes[1] / 2;     // 800000 edges
    const int* src = ei;
    const int* dst = ei + E;

    char* w = (char*)d_ws;
    auto alloc = [&](size_t bytes) -> void* {
        void* p = (void*)w;
        w += (bytes + 255) & ~(size_t)255;
        return p;
    };
    int*   deg     = (int*)alloc((size_t)M * 4);
    float* dinv    = (float*)alloc((size_t)M * 4);
    int*   row_ptr = (int*)alloc((size_t)(M + 1) * 4);
    int*   cursor  = (int*)alloc((size_t)M * 4);
    int*   bsum    = (int*)alloc(64 * 4);
    int*   col     = (int*)alloc((size_t)E * 4);
    float* bufA    = (float*)alloc((size_t)M * NCH * 4);
    float* bufB    = (float*)alloc((size_t)M * NCH * 4);

    const int nb = (M + 1023) / 1024;  // 49 <= 64

    // CSR build
    k_init_deg<<<(M + 255) / 256, 256, 0, stream>>>(deg, M);
    k_hist<<<(E + 255) / 256, 256, 0, stream>>>(dst, E, deg);
    k_scan_blk<<<nb, 256, 0, stream>>>(deg, row_ptr, bsum, M);
    k_scan_top<<<1, 64, 0, stream>>>(bsum, nb, row_ptr + M);
    k_finalize<<<(M + 255) / 256, 256, 0, stream>>>(deg, row_ptr, bsum, cursor, dinv, M);
    k_scatter<<<(E + 255) / 256, 256, 0, stream>>>(src, dst, E, cursor, col);

    dim3 ggrid((M + 63) / 64, NCH / 64);

    // layer 1
    k_gemm_f32<<<ggrid, 256, 0, stream>>>(x, W1, bufA, M);
    k_agg<<<M, 256, 0, stream>>>(bufA, dinv, row_ptr, col, b1, bufB);
    // layer 2
    k_gemm_f32<<<ggrid, 256, 0, stream>>>(bufB, W2, bufA, M);
    k_agg<<<M, 256, 0, stream>>>(bufA, dinv, row_ptr, col, b2, bufB);
    // pool
    k_pool<<<128, 256, 0, stream>>>(bufB, batch, out, M);
}

// Round 2
// 454.025 us; speedup vs baseline: 1.4019x; 1.4019x over previous
//
#include <hip/hip_runtime.h>

#define NCH 256   // channels (c_in == c_hid == 256)

typedef short short8 __attribute__((ext_vector_type(8)));
typedef float f32x4  __attribute__((ext_vector_type(4)));

__device__ __forceinline__ float b2f(unsigned short u) {
    union { unsigned int i; float f; } x; x.i = ((unsigned int)u) << 16; return x.f;
}
__device__ __forceinline__ unsigned short f2b(float f) {
    unsigned int u = __float_as_uint(f);
    unsigned int r = (u + 0x7FFFu + ((u >> 16) & 1u)) >> 16;   // RNE
    return (unsigned short)r;
}

#define GLOAD_LDS16(gptr, lptr) \
    __builtin_amdgcn_global_load_lds((const __attribute__((address_space(1))) void*)(gptr), \
                                     (__attribute__((address_space(3))) void*)(lptr), 16, 0, 0)

// ---------------- CSR build ----------------
__global__ __launch_bounds__(256) void k_init_deg(int* __restrict__ deg, int n) {
    int i = blockIdx.x * 256 + threadIdx.x;
    if (i < n) deg[i] = 1;  // self-loop
}

__global__ __launch_bounds__(256) void k_hist(const int* __restrict__ dst, int E,
                                              int* __restrict__ deg) {
    int e = blockIdx.x * 256 + threadIdx.x;
    if (e < E) atomicAdd(&deg[dst[e]], 1);
}

__global__ __launch_bounds__(256) void k_scan_blk(const int* __restrict__ deg,
                                                  int* __restrict__ part,
                                                  int* __restrict__ bsum, int N) {
    __shared__ int sm[256];
    int t = threadIdx.x;
    int base = blockIdx.x * 1024 + t * 4;
    int v[4]; int s = 0;
#pragma unroll
    for (int j = 0; j < 4; ++j) {
        int i = base + j;
        int d = (i < N) ? (deg[i] - 1) : 0;
        v[j] = d; s += d;
    }
    sm[t] = s; __syncthreads();
#pragma unroll
    for (int off = 1; off < 256; off <<= 1) {
        int u = (t >= off) ? sm[t - off] : 0;
        __syncthreads();
        sm[t] += u;
        __syncthreads();
    }
    int excl = sm[t] - s;
#pragma unroll
    for (int j = 0; j < 4; ++j) {
        int i = base + j;
        if (i < N) part[i] = excl;
        excl += v[j];
    }
    if (t == 255) bsum[blockIdx.x] = sm[255];
}

__global__ void k_scan_top(int* __restrict__ bsum, int nb, int* __restrict__ rowptr_end) {
    int t = threadIdx.x;  // 64 threads
    int orig = (t < nb) ? bsum[t] : 0;
    int v = orig;
#pragma unroll
    for (int off = 1; off < 64; off <<= 1) {
        int u = __shfl_up(v, off, 64);
        if (t >= off) v += u;
    }
    if (t < nb) bsum[t] = v - orig;
    if (t == 63) *rowptr_end = v;
}

__global__ __launch_bounds__(256) void k_finalize(const int* __restrict__ deg,
                                                  int* __restrict__ row_ptr,
                                                  const int* __restrict__ boff,
                                                  int* __restrict__ cursor,
                                                  float* __restrict__ dinv, int N) {
    int i = blockIdx.x * 256 + threadIdx.x;
    if (i < N) {
        int rp = row_ptr[i] + boff[i >> 10];
        row_ptr[i] = rp;
        cursor[i]  = rp;
        dinv[i] = rsqrtf((float)deg[i]);
    }
}

__global__ __launch_bounds__(256) void k_scatter(const int* __restrict__ src,
                                                 const int* __restrict__ dst, int E,
                                                 int* __restrict__ cursor,
                                                 int* __restrict__ col) {
    int e = blockIdx.x * 256 + threadIdx.x;
    if (e < E) {
        int d = dst[e];
        int pos = atomicAdd(&cursor[d], 1);
        col[pos] = src[e];
    }
}

// ---------------- casts ----------------
__global__ __launch_bounds__(256) void k_cast8(const float* __restrict__ in,
                                               unsigned short* __restrict__ out, int n8) {
    int i = blockIdx.x * 256 + threadIdx.x;
    if (i < n8) {
        const float4* p = (const float4*)(in + (size_t)i * 8);
        float4 a = p[0], b = p[1];
        unsigned short us[8];
        us[0] = f2b(a.x); us[1] = f2b(a.y); us[2] = f2b(a.z); us[3] = f2b(a.w);
        us[4] = f2b(b.x); us[5] = f2b(b.y); us[6] = f2b(b.z); us[7] = f2b(b.w);
        *(int4*)(out + (size_t)i * 8) = *(const int4*)us;
    }
}

// W[k][n] f32 -> Wt[n][k] bf16 (both 256x256), y selects which weight
__global__ __launch_bounds__(256) void k_castT(const float* __restrict__ W1,
                                               const float* __restrict__ W2,
                                               unsigned short* __restrict__ Wt1,
                                               unsigned short* __restrict__ Wt2) {
    int k = blockIdx.x, n = threadIdx.x;
    const float* W = blockIdx.y ? W2 : W1;
    unsigned short* Wt = blockIdx.y ? Wt2 : Wt1;
    Wt[(size_t)n * 256 + k] = f2b(W[(size_t)k * 256 + n]);
}

// ---------------- bf16 MFMA GEMM: C[M,256] = A[M,256] @ W, W given as Wt[n][k] ----
// 128x128 tile, 256 threads (4 waves, 2x2), wave computes 64x64 = 4x4 frags of 16x16.
// BK=32. LDS tiles [128][32] bf16, k-unit (16B) XOR-swizzled by (row&3) for banks.
__global__ __launch_bounds__(256) void k_gemm_bf16(const unsigned short* __restrict__ A,
                                                   const unsigned short* __restrict__ Bt,
                                                   unsigned short* __restrict__ C, int M) {
    __shared__ unsigned short As[128 * 32];
    __shared__ unsigned short Bs[128 * 32];

    const int tid  = threadIdx.x;
    const int wid  = tid >> 6;
    const int lane = tid & 63;
    const int m0 = blockIdx.x * 128;
    const int n0 = blockIdx.y * 128;
    const int wr = wid >> 1, wc = wid & 1;

    // staging: thread t stages 16B unit (row = t>>2 [+64], kcu = (t&3) ^ (row&3))
    const int srow = tid >> 2;
    const int skc  = (((tid & 3) ^ (srow & 3)) << 3);   // swizzled k offset (elems)
    int arow0 = m0 + srow;       if (arow0 >= M) arow0 = M - 1;
    int arow1 = m0 + srow + 64;  if (arow1 >= M) arow1 = M - 1;
    const int brow0 = n0 + srow;
    const int brow1 = n0 + srow + 64;

    const unsigned short* gA0 = A  + (size_t)arow0 * NCH + skc;
    const unsigned short* gA1 = A  + (size_t)arow1 * NCH + skc;
    const unsigned short* gB0 = Bt + (size_t)brow0 * NCH + skc;
    const unsigned short* gB1 = Bt + (size_t)brow1 * NCH + skc;

    unsigned short* ldsA0 = As + (wid << 9);            // wave-uniform dest
    unsigned short* ldsA1 = As + 2048 + (wid << 9);
    unsigned short* ldsB0 = Bs + (wid << 9);
    unsigned short* ldsB1 = Bs + 2048 + (wid << 9);

    f32x4 acc[4][4];
#pragma unroll
    for (int i = 0; i < 4; ++i)
#pragma unroll
        for (int j = 0; j < 4; ++j) acc[i][j] = (f32x4){0.f, 0.f, 0.f, 0.f};

    const int lr = lane & 15;
    const int kcu = lane >> 4;          // 0..3 k-unit

    for (int k0 = 0; k0 < 256; k0 += 32) {
        __syncthreads();                 // all waves done reading LDS
        GLOAD_LDS16(gA0 + k0, ldsA0);
        GLOAD_LDS16(gA1 + k0, ldsA1);
        GLOAD_LDS16(gB0 + k0, ldsB0);
        GLOAD_LDS16(gB1 + k0, ldsB1);
        __syncthreads();                 // vmcnt drained before barrier

        short8 af[4], bfr[4];
#pragma unroll
        for (int mf = 0; mf < 4; ++mf) {
            int row = wr * 64 + mf * 16 + lr;
            int lk = ((kcu ^ (row & 3)) << 3);
            af[mf] = *(const short8*)&As[row * 32 + lk];
        }
#pragma unroll
        for (int nf = 0; nf < 4; ++nf) {
            int row = wc * 64 + nf * 16 + lr;
            int lk = ((kcu ^ (row & 3)) << 3);
            bfr[nf] = *(const short8*)&Bs[row * 32 + lk];
        }
#pragma unroll
        for (int mf = 0; mf < 4; ++mf)
#pragma unroll
            for (int nf = 0; nf < 4; ++nf)
                acc[mf][nf] = __builtin_amdgcn_mfma_f32_16x16x32_bf16(af[mf], bfr[nf],
                                                                      acc[mf][nf], 0, 0, 0);
    }

    // C/D layout: col = lane&15, row = (lane>>4)*4 + r   [m89-verified]
#pragma unroll
    for (int mf = 0; mf < 4; ++mf) {
#pragma unroll
        for (int nf = 0; nf < 4; ++nf) {
            int rb = m0 + wr * 64 + mf * 16 + ((lane >> 4) << 2);
            int cc = n0 + wc * 64 + nf * 16 + lr;
#pragma unroll
            for (int r = 0; r < 4; ++r) {
                int row = rb + r;
                if (row < M) C[(size_t)row * NCH + cc] = f2b(acc[mf][nf][r]);
            }
        }
    }
}

// ---------------- aggregation over bf16 rows ----------------
__global__ __launch_bounds__(256) void k_agg_b(const unsigned short* __restrict__ h,
                                               const float* __restrict__ dinv,
                                               const int* __restrict__ row_ptr,
                                               const int* __restrict__ col,
                                               const float* __restrict__ bias,
                                               unsigned short* __restrict__ out) {
    __shared__ int   scol[256];
    __shared__ float sdw[256];
    int v = blockIdx.x;
    int ch = threadIdx.x;
    float dv = dinv[v];
    float acc = dv * b2f(h[(size_t)v * NCH + ch]);   // self-loop
    int beg = row_ptr[v], end = row_ptr[v + 1];
    for (int cb = beg; cb < end; cb += 256) {
        int n = min(256, end - cb);
        __syncthreads();
        if (ch < n) {
            int s = col[cb + ch];
            scol[ch] = s;
            sdw[ch] = dinv[s];
        }
        __syncthreads();
#pragma unroll 4
        for (int j = 0; j < n; ++j) {
            acc += sdw[j] * b2f(h[(size_t)scol[j] * NCH + ch]);
        }
    }
    float r = fmaxf(dv * acc + bias[ch], 0.0f);
    out[(size_t)v * NCH + ch] = f2b(r);
}

// ---------------- mean pool over sorted batch ids ----------------
__device__ __forceinline__ int lower_bound_i(const int* a, int n, int key) {
    int lo = 0, hi = n;
    while (lo < hi) {
        int mid = (lo + hi) >> 1;
        if (a[mid] < key) lo = mid + 1; else hi = mid;
    }
    return lo;
}

__global__ __launch_bounds__(256) void k_pool(const unsigned short* __restrict__ a,
                                              const int* __restrict__ batch,
                                              float* __restrict__ out, int N) {
    int g = blockIdx.x;
    int ch = threadIdx.x;
    int lo = lower_bound_i(batch, N, g);
    int hi = lower_bound_i(batch, N, g + 1);
    float s = 0.0f;
    for (int i = lo; i < hi; ++i) s += b2f(a[(size_t)i * NCH + ch]);
    int cnt = hi - lo;
    out[(size_t)g * NCH + ch] = s / (float)max(cnt, 1);
}

// ---------------- host ----------------
extern "C" void kernel_launch(void* const* d_in, const int* in_sizes, int n_in,
                              void* d_out, int out_size, void* d_ws, size_t ws_size,
                              hipStream_t stream) {
    const float* x     = (const float*)d_in[0];
    const int*   ei    = (const int*)d_in[1];
    const int*   batch = (const int*)d_in[2];
    const float* W1    = (const float*)d_in[3];
    const float* b1    = (const float*)d_in[4];
    const float* W2    = (const float*)d_in[5];
    const float* b2    = (const float*)d_in[6];
    float* out = (float*)d_out;

    const int M = in_sizes[0] / NCH;   // 50000
    const int E = in_sizes[1] / 2;     // 800000
    const int* src = ei;
    const int* dst = ei + E;

    char* w = (char*)d_ws;
    auto alloc = [&](size_t bytes) -> void* {
        void* p = (void*)w;
        w += (bytes + 255) & ~(size_t)255;
        return p;
    };
    int*   deg     = (int*)alloc((size_t)M * 4);
    float* dinv    = (float*)alloc((size_t)M * 4);
    int*   row_ptr = (int*)alloc((size_t)(M + 1) * 4);
    int*   cursor  = (int*)alloc((size_t)M * 4);
    int*   bsum    = (int*)alloc(64 * 4);
    int*   col     = (int*)alloc((size_t)E * 4);
    unsigned short* xb   = (unsigned short*)alloc((size_t)M * NCH * 2);
    unsigned short* bufP = (unsigned short*)alloc((size_t)M * NCH * 2);
    unsigned short* bufQ = (unsigned short*)alloc((size_t)M * NCH * 2);
    unsigned short* Wt1  = (unsigned short*)alloc((size_t)NCH * NCH * 2);
    unsigned short* Wt2  = (unsigned short*)alloc((size_t)NCH * NCH * 2);

    const int nb = (M + 1023) / 1024;

    // casts (independent of CSR)
    k_cast8<<<(M * NCH / 8 + 255) / 256, 256, 0, stream>>>(x, xb, M * NCH / 8);
    k_castT<<<dim3(256, 2), 256, 0, stream>>>(W1, W2, Wt1, Wt2);

    // CSR build
    k_init_deg<<<(M + 255) / 256, 256, 0, stream>>>(deg, M);
    k_hist<<<(E + 255) / 256, 256, 0, stream>>>(dst, E, deg);
    k_scan_blk<<<nb, 256, 0, stream>>>(deg, row_ptr, bsum, M);
    k_scan_top<<<1, 64, 0, stream>>>(bsum, nb, row_ptr + M);
    k_finalize<<<(M + 255) / 256, 256, 0, stream>>>(deg, row_ptr, bsum, cursor, dinv, M);
    k_scatter<<<(E + 255) / 256, 256, 0, stream>>>(src, dst, E, cursor, col);

    dim3 ggrid((M + 127) / 128, NCH / 128);

    // layer 1
    k_gemm_bf16<<<ggrid, 256, 0, stream>>>(xb, Wt1, bufP, M);
    k_agg_b<<<M, 256, 0, stream>>>(bufP, dinv, row_ptr, col, b1, bufQ);
    // layer 2
    k_gemm_bf16<<<ggrid, 256, 0, stream>>>(bufQ, Wt2, bufP, M);
    k_agg_b<<<M, 256, 0, stream>>>(bufP, dinv, row_ptr, col, b2, bufQ);
    // pool
    k_pool<<<128, 256, 0, stream>>>(bufQ, batch, out, M);
}

// Round 3
// 303.298 us; speedup vs baseline: 2.0986x; 1.4970x over previous
//
#include <hip/hip_runtime.h>

#define NCH 256   // channels (c_in == c_hid == 256)
#define NS  16    // pool slices per graph

typedef short short8 __attribute__((ext_vector_type(8)));
typedef float f32x4  __attribute__((ext_vector_type(4)));

__device__ __forceinline__ float b2f(unsigned short u) {
    union { unsigned int i; float f; } x; x.i = ((unsigned int)u) << 16; return x.f;
}
__device__ __forceinline__ unsigned short f2b(float f) {
    unsigned int u = __float_as_uint(f);
    unsigned int r = (u + 0x7FFFu + ((u >> 16) & 1u)) >> 16;   // RNE
    return (unsigned short)r;
}

#define GLOAD_LDS16(gptr, lptr) \
    __builtin_amdgcn_global_load_lds((const __attribute__((address_space(1))) void*)(gptr), \
                                     (__attribute__((address_space(3))) void*)(lptr), 16, 0, 0)

// ---------------- CSR build ----------------
__global__ __launch_bounds__(256) void k_init_deg(int* __restrict__ deg, int n) {
    int i = blockIdx.x * 256 + threadIdx.x;
    if (i < n) deg[i] = 1;  // self-loop
}

__global__ __launch_bounds__(256) void k_hist(const int* __restrict__ dst, int E,
                                              int* __restrict__ deg) {
    int e = blockIdx.x * 256 + threadIdx.x;
    if (e < E) atomicAdd(&deg[dst[e]], 1);
}

__global__ __launch_bounds__(256) void k_scan_blk(const int* __restrict__ deg,
                                                  int* __restrict__ part,
                                                  int* __restrict__ bsum, int N) {
    __shared__ int sm[256];
    int t = threadIdx.x;
    int base = blockIdx.x * 1024 + t * 4;
    int v[4]; int s = 0;
#pragma unroll
    for (int j = 0; j < 4; ++j) {
        int i = base + j;
        int d = (i < N) ? (deg[i] - 1) : 0;
        v[j] = d; s += d;
    }
    sm[t] = s; __syncthreads();
#pragma unroll
    for (int off = 1; off < 256; off <<= 1) {
        int u = (t >= off) ? sm[t - off] : 0;
        __syncthreads();
        sm[t] += u;
        __syncthreads();
    }
    int excl = sm[t] - s;
#pragma unroll
    for (int j = 0; j < 4; ++j) {
        int i = base + j;
        if (i < N) part[i] = excl;
        excl += v[j];
    }
    if (t == 255) bsum[blockIdx.x] = sm[255];
}

__global__ void k_scan_top(int* __restrict__ bsum, int nb, int* __restrict__ rowptr_end) {
    int t = threadIdx.x;  // 64 threads
    int orig = (t < nb) ? bsum[t] : 0;
    int v = orig;
#pragma unroll
    for (int off = 1; off < 64; off <<= 1) {
        int u = __shfl_up(v, off, 64);
        if (t >= off) v += u;
    }
    if (t < nb) bsum[t] = v - orig;
    if (t == 63) *rowptr_end = v;
}

__global__ __launch_bounds__(256) void k_finalize(const int* __restrict__ deg,
                                                  int* __restrict__ row_ptr,
                                                  const int* __restrict__ boff,
                                                  int* __restrict__ cursor,
                                                  float* __restrict__ dinv, int N) {
    int i = blockIdx.x * 256 + threadIdx.x;
    if (i < N) {
        int rp = row_ptr[i] + boff[i >> 10];
        row_ptr[i] = rp;
        cursor[i]  = rp;
        dinv[i] = rsqrtf((float)deg[i]);
    }
}

__global__ __launch_bounds__(256) void k_scatter(const int* __restrict__ src,
                                                 const int* __restrict__ dst, int E,
                                                 int* __restrict__ cursor,
                                                 int* __restrict__ col) {
    int e = blockIdx.x * 256 + threadIdx.x;
    if (e < E) {
        int d = dst[e];
        int pos = atomicAdd(&cursor[d], 1);
        col[pos] = src[e];
    }
}

// ---------------- casts ----------------
__global__ __launch_bounds__(256) void k_cast8(const float* __restrict__ in,
                                               unsigned short* __restrict__ out, int n8) {
    int i = blockIdx.x * 256 + threadIdx.x;
    if (i < n8) {
        const float4* p = (const float4*)(in + (size_t)i * 8);
        float4 a = p[0], b = p[1];
        unsigned short us[8];
        us[0] = f2b(a.x); us[1] = f2b(a.y); us[2] = f2b(a.z); us[3] = f2b(a.w);
        us[4] = f2b(b.x); us[5] = f2b(b.y); us[6] = f2b(b.z); us[7] = f2b(b.w);
        *(int4*)(out + (size_t)i * 8) = *(const int4*)us;
    }
}

// W[k][n] f32 -> Wt[n][k] bf16 (both 256x256)
__global__ __launch_bounds__(256) void k_castT(const float* __restrict__ W1,
                                               const float* __restrict__ W2,
                                               unsigned short* __restrict__ Wt1,
                                               unsigned short* __restrict__ Wt2) {
    int k = blockIdx.x, n = threadIdx.x;
    const float* W = blockIdx.y ? W2 : W1;
    unsigned short* Wt = blockIdx.y ? Wt2 : Wt1;
    Wt[(size_t)n * 256 + k] = f2b(W[(size_t)k * 256 + n]);
}

// ---------------- bf16 MFMA GEMM: C[M,256] = A[M,256] @ W (Wt[n][k]) ----------------
__global__ __launch_bounds__(256) void k_gemm_bf16(const unsigned short* __restrict__ A,
                                                   const unsigned short* __restrict__ Bt,
                                                   unsigned short* __restrict__ C, int M) {
    __shared__ unsigned short As[128 * 32];
    __shared__ unsigned short Bs[128 * 32];

    const int tid  = threadIdx.x;
    const int wid  = tid >> 6;
    const int lane = tid & 63;
    const int m0 = blockIdx.x * 128;
    const int n0 = blockIdx.y * 128;
    const int wr = wid >> 1, wc = wid & 1;

    const int srow = tid >> 2;
    const int skc  = (((tid & 3) ^ (srow & 3)) << 3);
    int arow0 = m0 + srow;       if (arow0 >= M) arow0 = M - 1;
    int arow1 = m0 + srow + 64;  if (arow1 >= M) arow1 = M - 1;
    const int brow0 = n0 + srow;
    const int brow1 = n0 + srow + 64;

    const unsigned short* gA0 = A  + (size_t)arow0 * NCH + skc;
    const unsigned short* gA1 = A  + (size_t)arow1 * NCH + skc;
    const unsigned short* gB0 = Bt + (size_t)brow0 * NCH + skc;
    const unsigned short* gB1 = Bt + (size_t)brow1 * NCH + skc;

    unsigned short* ldsA0 = As + (wid << 9);
    unsigned short* ldsA1 = As + 2048 + (wid << 9);
    unsigned short* ldsB0 = Bs + (wid << 9);
    unsigned short* ldsB1 = Bs + 2048 + (wid << 9);

    f32x4 acc[4][4];
#pragma unroll
    for (int i = 0; i < 4; ++i)
#pragma unroll
        for (int j = 0; j < 4; ++j) acc[i][j] = (f32x4){0.f, 0.f, 0.f, 0.f};

    const int lr = lane & 15;
    const int kcu = lane >> 4;

    for (int k0 = 0; k0 < 256; k0 += 32) {
        __syncthreads();
        GLOAD_LDS16(gA0 + k0, ldsA0);
        GLOAD_LDS16(gA1 + k0, ldsA1);
        GLOAD_LDS16(gB0 + k0, ldsB0);
        GLOAD_LDS16(gB1 + k0, ldsB1);
        __syncthreads();

        short8 af[4], bfr[4];
#pragma unroll
        for (int mf = 0; mf < 4; ++mf) {
            int row = wr * 64 + mf * 16 + lr;
            int lk = ((kcu ^ (row & 3)) << 3);
            af[mf] = *(const short8*)&As[row * 32 + lk];
        }
#pragma unroll
        for (int nf = 0; nf < 4; ++nf) {
            int row = wc * 64 + nf * 16 + lr;
            int lk = ((kcu ^ (row & 3)) << 3);
            bfr[nf] = *(const short8*)&Bs[row * 32 + lk];
        }
#pragma unroll
        for (int mf = 0; mf < 4; ++mf)
#pragma unroll
            for (int nf = 0; nf < 4; ++nf)
                acc[mf][nf] = __builtin_amdgcn_mfma_f32_16x16x32_bf16(af[mf], bfr[nf],
                                                                      acc[mf][nf], 0, 0, 0);
    }

#pragma unroll
    for (int mf = 0; mf < 4; ++mf) {
#pragma unroll
        for (int nf = 0; nf < 4; ++nf) {
            int rb = m0 + wr * 64 + mf * 16 + ((lane >> 4) << 2);
            int cc = n0 + wc * 64 + nf * 16 + lr;
#pragma unroll
            for (int r = 0; r < 4; ++r) {
                int row = rb + r;
                if (row < M) C[(size_t)row * NCH + cc] = f2b(acc[mf][nf][r]);
            }
        }
    }
}

// ---------------- aggregation: wave-per-node, short8 lanes, 2 neighbor streams ----
__global__ __launch_bounds__(256) void k_agg_w(const unsigned short* __restrict__ h,
                                               const float* __restrict__ dinv,
                                               const int* __restrict__ row_ptr,
                                               const int* __restrict__ col,
                                               const float* __restrict__ bias,
                                               unsigned short* __restrict__ out, int M) {
    int v = blockIdx.x * 4 + (threadIdx.x >> 6);
    if (v >= M) return;                      // no barriers below: safe
    const int lane = threadIdx.x & 63;
    const int half = lane >> 5;              // neighbor stream 0/1
    const int cb   = (lane & 31) << 3;       // channel base (8 per lane)

    float acc[8] = {};
    float dv = dinv[v];

    if (half == 0) {                         // self-loop contribution
        short8 hv = *(const short8*)&h[(size_t)v * NCH + cb];
#pragma unroll
        for (int i = 0; i < 8; ++i) acc[i] += dv * b2f((unsigned short)hv[i]);
    }

    int beg = row_ptr[v], end = row_ptr[v + 1];
    for (int idx = beg + half; idx < end; idx += 2) {
        int s = col[idx];
        float ws = dinv[s];
        short8 hs = *(const short8*)&h[(size_t)s * NCH + cb];
#pragma unroll
        for (int i = 0; i < 8; ++i) acc[i] += ws * b2f((unsigned short)hs[i]);
    }

#pragma unroll
    for (int i = 0; i < 8; ++i) acc[i] += __shfl_xor(acc[i], 32, 64);

    if (half == 0) {
        f32x4 bl = *(const f32x4*)&bias[cb];
        f32x4 bh = *(const f32x4*)&bias[cb + 4];
        unsigned short us[8];
#pragma unroll
        for (int i = 0; i < 8; ++i) {
            float b = (i < 4) ? bl[i] : bh[i - 4];
            us[i] = f2b(fmaxf(dv * acc[i] + b, 0.0f));
        }
        *(int4*)&out[(size_t)v * NCH + cb] = *(const int4*)us;
    }
}

// ---------------- mean pool, two-phase ----------------
__device__ __forceinline__ int lower_bound_i(const int* a, int n, int key) {
    int lo = 0, hi = n;
    while (lo < hi) {
        int mid = (lo + hi) >> 1;
        if (a[mid] < key) lo = mid + 1; else hi = mid;
    }
    return lo;
}

// phase A: one wave per (graph, slice); 32 lanes x 8ch, 2 row streams
__global__ __launch_bounds__(64) void k_pool_a(const unsigned short* __restrict__ a,
                                               const int* __restrict__ batch,
                                               float* __restrict__ partial, int N) {
    int g = blockIdx.x, s = blockIdx.y;
    const int lane = threadIdx.x;
    const int half = lane >> 5;
    const int cb   = (lane & 31) << 3;

    int lo = lower_bound_i(batch, N, g);
    int hi = lower_bound_i(batch, N, g + 1);
    int cnt = hi - lo;
    int len = (cnt + NS - 1) / NS;
    int rlo = lo + s * len;
    int rhi = min(rlo + len, hi);

    float acc[8] = {};
    for (int r = rlo + half; r < rhi; r += 2) {
        short8 hv = *(const short8*)&a[(size_t)r * NCH + cb];
#pragma unroll
        for (int i = 0; i < 8; ++i) acc[i] += b2f((unsigned short)hv[i]);
    }
#pragma unroll
    for (int i = 0; i < 8; ++i) acc[i] += __shfl_xor(acc[i], 32, 64);

    if (half == 0) {
        float* p = partial + ((size_t)g * NS + s) * NCH + cb;
        *(f32x4*)p       = (f32x4){acc[0], acc[1], acc[2], acc[3]};
        *(f32x4*)(p + 4) = (f32x4){acc[4], acc[5], acc[6], acc[7]};
    }
}

// phase B: 128 blocks x 256 thr: sum NS partials, divide by count
__global__ __launch_bounds__(256) void k_pool_b(const float* __restrict__ partial,
                                                const int* __restrict__ batch,
                                                float* __restrict__ out, int N) {
    int g = blockIdx.x, ch = threadIdx.x;
    int lo = lower_bound_i(batch, N, g);
    int hi = lower_bound_i(batch, N, g + 1);
    float s = 0.0f;
#pragma unroll
    for (int k = 0; k < NS; ++k)
        s += partial[((size_t)g * NS + k) * NCH + ch];
    out[(size_t)g * NCH + ch] = s / (float)max(hi - lo, 1);
}

// ---------------- host ----------------
extern "C" void kernel_launch(void* const* d_in, const int* in_sizes, int n_in,
                              void* d_out, int out_size, void* d_ws, size_t ws_size,
                              hipStream_t stream) {
    const float* x     = (const float*)d_in[0];
    const int*   ei    = (const int*)d_in[1];
    const int*   batch = (const int*)d_in[2];
    const float* W1    = (const float*)d_in[3];
    const float* b1    = (const float*)d_in[4];
    const float* W2    = (const float*)d_in[5];
    const float* b2    = (const float*)d_in[6];
    float* out = (float*)d_out;

    const int M = in_sizes[0] / NCH;   // 50000
    const int E = in_sizes[1] / 2;     // 800000
    const int* src = ei;
    const int* dst = ei + E;

    char* w = (char*)d_ws;
    auto alloc = [&](size_t bytes) -> void* {
        void* p = (void*)w;
        w += (bytes + 255) & ~(size_t)255;
        return p;
    };
    int*   deg     = (int*)alloc((size_t)M * 4);
    float* dinv    = (float*)alloc((size_t)M * 4);
    int*   row_ptr = (int*)alloc((size_t)(M + 1) * 4);
    int*   cursor  = (int*)alloc((size_t)M * 4);
    int*   bsum    = (int*)alloc(64 * 4);
    int*   col     = (int*)alloc((size_t)E * 4);
    unsigned short* xb   = (unsigned short*)alloc((size_t)M * NCH * 2);
    unsigned short* bufP = (unsigned short*)alloc((size_t)M * NCH * 2);
    unsigned short* bufQ = (unsigned short*)alloc((size_t)M * NCH * 2);
    unsigned short* Wt1  = (unsigned short*)alloc((size_t)NCH * NCH * 2);
    unsigned short* Wt2  = (unsigned short*)alloc((size_t)NCH * NCH * 2);
    float* partial = (float*)alloc((size_t)128 * NS * NCH * 4);

    const int nb = (M + 1023) / 1024;

    k_cast8<<<(M * NCH / 8 + 255) / 256, 256, 0, stream>>>(x, xb, M * NCH / 8);
    k_castT<<<dim3(256, 2), 256, 0, stream>>>(W1, W2, Wt1, Wt2);

    k_init_deg<<<(M + 255) / 256, 256, 0, stream>>>(deg, M);
    k_hist<<<(E + 255) / 256, 256, 0, stream>>>(dst, E, deg);
    k_scan_blk<<<nb, 256, 0, stream>>>(deg, row_ptr, bsum, M);
    k_scan_top<<<1, 64, 0, stream>>>(bsum, nb, row_ptr + M);
    k_finalize<<<(M + 255) / 256, 256, 0, stream>>>(deg, row_ptr, bsum, cursor, dinv, M);
    k_scatter<<<(E + 255) / 256, 256, 0, stream>>>(src, dst, E, cursor, col);

    dim3 ggrid((M + 127) / 128, NCH / 128);

    // layer 1
    k_gemm_bf16<<<ggrid, 256, 0, stream>>>(xb, Wt1, bufP, M);
    k_agg_w<<<(M + 3) / 4, 256, 0, stream>>>(bufP, dinv, row_ptr, col, b1, bufQ, M);
    // layer 2
    k_gemm_bf16<<<ggrid, 256, 0, stream>>>(bufQ, Wt2, bufP, M);
    k_agg_w<<<(M + 3) / 4, 256, 0, stream>>>(bufP, dinv, row_ptr, col, b2, bufQ, M);
    // pool
    k_pool_a<<<dim3(128, NS), 64, 0, stream>>>(bufQ, batch, partial, M);
    k_pool_b<<<128, 256, 0, stream>>>(partial, batch, out, M);
}